// Round 6
// baseline (204.210 us; speedup 1.0000x reference)
//
#include <hip/hip_runtime.h>
#include <cstddef>

#define B_SZ 16
#define HW 1024
#define CCH 512
#define K_LEN 256
#define N_HEADS 8
#define EPS 1e-5f

typedef __bf16 bf16;
typedef bf16 bf16x8 __attribute__((ext_vector_type(8)));
typedef bf16 bf16x4 __attribute__((ext_vector_type(4)));
typedef float f32x4 __attribute__((ext_vector_type(4)));

// async global->LDS, 16B per lane; LDS dest is wave-uniform base + lane*16
__device__ __forceinline__ void gl_lds16(const bf16* g, bf16* l) {
    __builtin_amdgcn_global_load_lds(
        (const __attribute__((address_space(1))) void*)g,
        (__attribute__((address_space(3))) void*)l, 16, 0, 0);
}

// ---------------------------------------------------------------------------
// Transpose+cast img: [B][512][1024] f32 -> [B][1024][512] bf16
// (feeds the Q-projection GEMM's A operand only; residual uses raw img)
// ---------------------------------------------------------------------------
__global__ __launch_bounds__(256) void transpose_cast_img(
    const float* __restrict__ src, bf16* __restrict__ dst)
{
    const int b  = blockIdx.z;
    const int s0 = blockIdx.x * 64;
    const int c0 = blockIdx.y * 64;
    __shared__ bf16 T[64][72];
    const int tid = threadIdx.x;
    {
        const int r = tid >> 2, cs = (tid & 3) << 4;
        const float* sp = src + ((size_t)b * CCH + c0 + r) * HW + s0 + cs;
        #pragma unroll
        for (int i = 0; i < 4; ++i) {
            float4 f = *(const float4*)(sp + i * 4);
            T[r][cs + i*4 + 0] = (bf16)f.x;
            T[r][cs + i*4 + 1] = (bf16)f.y;
            T[r][cs + i*4 + 2] = (bf16)f.z;
            T[r][cs + i*4 + 3] = (bf16)f.w;
        }
    }
    __syncthreads();
    {
        const int ss = tid >> 2, ks = (tid & 3) << 4;
        bf16x8 a, b8;
        #pragma unroll
        for (int j = 0; j < 8; ++j) { a[j] = T[ks + j][ss]; b8[j] = T[ks + 8 + j][ss]; }
        bf16* dp = dst + ((size_t)b * HW + s0 + ss) * CCH + c0 + ks;
        *(bf16x8*)dp = a;
        *(bf16x8*)(dp + 8) = b8;
    }
}

// ---------------------------------------------------------------------------
// Transpose+cast weights: W[k][n] f32 -> Wt[n][k] bf16, packed [4][512][512]
// ---------------------------------------------------------------------------
__global__ __launch_bounds__(256) void transpose_cast_w(
    const float* __restrict__ Wq, const float* __restrict__ Wk,
    const float* __restrict__ Wv, const float* __restrict__ Wo,
    bf16* __restrict__ dst)
{
    const int w = blockIdx.z;
    const float* src = (w == 0) ? Wq : (w == 1) ? Wk : (w == 2) ? Wv : Wo;
    const int n0 = blockIdx.x * 64;
    const int k0 = blockIdx.y * 64;
    __shared__ bf16 T[64][72];
    const int tid = threadIdx.x;
    {
        const int r = tid >> 2, cs = (tid & 3) << 4;
        const float* sp = src + (size_t)(k0 + r) * CCH + n0 + cs;
        #pragma unroll
        for (int i = 0; i < 4; ++i) {
            float4 f = *(const float4*)(sp + i * 4);
            T[r][cs + i*4 + 0] = (bf16)f.x;
            T[r][cs + i*4 + 1] = (bf16)f.y;
            T[r][cs + i*4 + 2] = (bf16)f.z;
            T[r][cs + i*4 + 3] = (bf16)f.w;
        }
    }
    __syncthreads();
    {
        const int nn = tid >> 2, ks = (tid & 3) << 4;
        bf16x8 a, b8;
        #pragma unroll
        for (int j = 0; j < 8; ++j) { a[j] = T[ks + j][nn]; b8[j] = T[ks + 8 + j][nn]; }
        bf16* dp = dst + (size_t)w * CCH * CCH + (size_t)(n0 + nn) * CCH + k0 + ks;
        *(bf16x8*)dp = a;
        *(bf16x8*)(dp + 8) = b8;
    }
}

// ---------------------------------------------------------------------------
// Q projection GEMM (m97-style): out[m][n] = sum_k A[m][k]*Bt[n][k] + bias[n]
// 128x128 tile, BK=32, gl_lds16 staging. Ct orientation -> 8B bf16x4 stores.
// ---------------------------------------------------------------------------
__global__ __launch_bounds__(256) void gemm_bf16_mfma(
    const bf16* __restrict__ A, const bf16* __restrict__ Bt,
    const float* __restrict__ bias, bf16* __restrict__ out)
{
    const int tid  = threadIdx.x;
    const int wave = tid >> 6, lane = tid & 63;
    const int m0 = blockIdx.x * 128;
    const int n0 = blockIdx.y * 128;
    const int l15 = lane & 15, quad = lane >> 4;
    const int wm = (wave >> 1) * 64, wn = (wave & 1) * 64;

    __shared__ bf16 As[128 * 32];
    __shared__ bf16 Bs[128 * 32];

    const int r16 = lane >> 2;
    const int ks  = (lane & 3) * 8;

    f32x4 acc[4][4];
    #pragma unroll
    for (int i = 0; i < 4; ++i)
        #pragma unroll
        for (int j = 0; j < 4; ++j)
            acc[i][j] = (f32x4){0.f, 0.f, 0.f, 0.f};

    for (int k0 = 0; k0 < 512; k0 += 32) {
        #pragma unroll
        for (int i = 0; i < 2; ++i) {
            const int c = wave * 2 + i;
            gl_lds16(A  + (size_t)(m0 + c * 16 + r16) * 512 + k0 + ks, &As[c * 512]);
            gl_lds16(Bt + (size_t)(n0 + c * 16 + r16) * 512 + k0 + ks, &Bs[c * 512]);
        }
        __syncthreads();
        bf16x8 af[4], bfr[4];
        #pragma unroll
        for (int i = 0; i < 4; ++i)
            af[i] = *(const bf16x8*)&As[(wm + i * 16 + l15) * 32 + quad * 8];
        #pragma unroll
        for (int j = 0; j < 4; ++j)
            bfr[j] = *(const bf16x8*)&Bs[(wn + j * 16 + l15) * 32 + quad * 8];
        #pragma unroll
        for (int i = 0; i < 4; ++i)
            #pragma unroll
            for (int j = 0; j < 4; ++j)
                acc[i][j] = __builtin_amdgcn_mfma_f32_16x16x32_bf16(bfr[j], af[i], acc[i][j], 0, 0, 0);
        __syncthreads();
    }

    #pragma unroll
    for (int j = 0; j < 4; ++j) {
        const int gn = n0 + wn + j * 16 + quad * 4;
        const f32x4 bv4 = *(const f32x4*)(bias + gn);
        #pragma unroll
        for (int i = 0; i < 4; ++i) {
            const int gm = m0 + wm + i * 16 + l15;
            bf16x4 ov;
            #pragma unroll
            for (int r = 0; r < 4; ++r) ov[r] = (bf16)(acc[i][j][r] + bv4[r]);
            *(bf16x4*)(out + (size_t)gm * 512 + gn) = ov;
        }
    }
}

// ---------------------------------------------------------------------------
// KV GEMM with fused f32->bf16 cast on the A side (reads raw audio f32).
//   cols <512  -> K row-major kh[b][h][key][64]
//   cols >=512 -> V transposed vt[b][h][d][256]
// ---------------------------------------------------------------------------
__global__ __launch_bounds__(256) void gemm_kv_mfma(
    const float* __restrict__ audio,  // [4096][512] f32
    const bf16* __restrict__ Bt,
    const float* __restrict__ bk, const float* __restrict__ bv,
    bf16* __restrict__ khout, bf16* __restrict__ vtout)
{
    const int tid  = threadIdx.x;
    const int wave = tid >> 6, lane = tid & 63;
    const int m0 = blockIdx.x * 128;
    const int n0 = blockIdx.y * 128;
    const int l15 = lane & 15, quad = lane >> 4;
    const int wm = (wave >> 1) * 64, wn = (wave & 1) * 64;

    __shared__ bf16 As[128 * 32];
    __shared__ bf16 Bs[128 * 32];

    const int r16 = lane >> 2;
    const int ks  = (lane & 3) * 8;

    f32x4 acc[4][4];
    #pragma unroll
    for (int i = 0; i < 4; ++i)
        #pragma unroll
        for (int j = 0; j < 4; ++j)
            acc[i][j] = (f32x4){0.f, 0.f, 0.f, 0.f};

    for (int k0 = 0; k0 < 512; k0 += 32) {
        // B via async 16B staging
        #pragma unroll
        for (int i = 0; i < 2; ++i) {
            const int c = wave * 2 + i;
            gl_lds16(Bt + (size_t)(n0 + c * 16 + r16) * 512 + k0 + ks, &Bs[c * 512]);
        }
        // A: load f32x8, cast, packed bf16x8 LDS write
        #pragma unroll
        for (int i = 0; i < 2; ++i) {
            const int u = tid + (i << 8);          // 0..511
            const int r = u >> 2, seg = (u & 3) << 3;
            const float* ap = audio + (size_t)(m0 + r) * 512 + k0 + seg;
            f32x4 a0 = *(const f32x4*)ap;
            f32x4 a1 = *(const f32x4*)(ap + 4);
            bf16x8 o;
            #pragma unroll
            for (int q = 0; q < 4; ++q) { o[q] = (bf16)a0[q]; o[q + 4] = (bf16)a1[q]; }
            *(bf16x8*)&As[r * 32 + seg] = o;
        }
        __syncthreads();
        bf16x8 af[4], bfr[4];
        #pragma unroll
        for (int i = 0; i < 4; ++i)
            af[i] = *(const bf16x8*)&As[(wm + i * 16 + l15) * 32 + quad * 8];
        #pragma unroll
        for (int j = 0; j < 4; ++j)
            bfr[j] = *(const bf16x8*)&Bs[(wn + j * 16 + l15) * 32 + quad * 8];
        #pragma unroll
        for (int i = 0; i < 4; ++i)
            #pragma unroll
            for (int j = 0; j < 4; ++j)
                acc[i][j] = __builtin_amdgcn_mfma_f32_16x16x32_bf16(af[i], bfr[j], acc[i][j], 0, 0, 0);
        __syncthreads();
    }

    #pragma unroll
    for (int j = 0; j < 4; ++j) {
        const int gn = n0 + wn + j * 16 + l15;
        if (gn < 512) {
            const int h = gn >> 6, d = gn & 63;
            const float bias = bk[gn];
            #pragma unroll
            for (int i = 0; i < 4; ++i) {
                const int gm = m0 + wm + i * 16 + quad * 4;
                const int b = gm >> 8, key = gm & 255;
                bf16* base = khout + ((((size_t)b * N_HEADS + h) * K_LEN) + key) * 64 + d;
                #pragma unroll
                for (int r = 0; r < 4; ++r)
                    base[(size_t)r * 64] = (bf16)(acc[i][j][r] + bias);
            }
        } else {
            const int ch = gn - 512;
            const int h = ch >> 6, d = ch & 63;
            const float bias = bv[ch];
            #pragma unroll
            for (int i = 0; i < 4; ++i) {
                const int gm = m0 + wm + i * 16 + quad * 4;
                const int b = gm >> 8, key = gm & 255;
                bf16x4 pk;
                #pragma unroll
                for (int r = 0; r < 4; ++r) pk[r] = (bf16)(acc[i][j][r] + bias);
                *(bf16x4*)(vtout + (((size_t)b * N_HEADS + h) * 64 + d) * K_LEN + key) = pk;
            }
        }
    }
}

// ---------------------------------------------------------------------------
// MFMA attention (unchanged): S^T trick + exact softmax + Vt@Pt.
// ---------------------------------------------------------------------------
__global__ __launch_bounds__(256) void attn_mfma(
    const bf16* __restrict__ q,    // [B*1024][512]
    const bf16* __restrict__ kh,   // [B][H][256][64]
    const bf16* __restrict__ vt,   // [B][H][64][256]
    bf16* __restrict__ o)          // [B*1024][512]
{
    const int bh = blockIdx.x;
    const int s0 = blockIdx.y * 64;
    const int tid = threadIdx.x;
    const int wave = tid >> 6, lane = tid & 63;
    const int l15 = lane & 15, quad = lane >> 4;
    const int b = bh >> 3, h = bh & 7;

    __shared__ bf16 KsPt[18432];   // Ks [256][72]; later Pt: 4 waves x [16][264]
    __shared__ bf16 Vs[16896];     // Vt [64][264]

    const bf16* khb = kh + (size_t)bh * K_LEN * 64;
    const bf16* vtb = vt + (size_t)bh * 64 * K_LEN;

    #pragma unroll
    for (int i = 0; i < 8; ++i) {
        const int chunk = tid + (i << 8);
        const int key = chunk >> 3, dseg = (chunk & 7) << 3;
        *(bf16x8*)&KsPt[key * 72 + dseg] = *(const bf16x8*)(khb + key * 64 + dseg);
        const int d = chunk >> 5, kseg = (chunk & 31) << 3;
        *(bf16x8*)&Vs[d * 264 + kseg] = *(const bf16x8*)(vtb + d * 256 + kseg);
    }
    __syncthreads();

    const int qrow = s0 + wave * 16 + l15;
    const bf16* qp = q + ((size_t)(b * HW + qrow)) * 512 + h * 64 + quad * 8;
    const bf16x8 qf0 = *(const bf16x8*)qp;
    const bf16x8 qf1 = *(const bf16x8*)(qp + 32);

    f32x4 acc[16];
    #pragma unroll
    for (int m = 0; m < 16; ++m) acc[m] = (f32x4){0.f, 0.f, 0.f, 0.f};
    #pragma unroll
    for (int m = 0; m < 16; ++m) {
        const bf16x8 a0 = *(const bf16x8*)&KsPt[(m * 16 + l15) * 72 + quad * 8];
        const bf16x8 a1 = *(const bf16x8*)&KsPt[(m * 16 + l15) * 72 + 32 + quad * 8];
        acc[m] = __builtin_amdgcn_mfma_f32_16x16x32_bf16(a0, qf0, acc[m], 0, 0, 0);
        acc[m] = __builtin_amdgcn_mfma_f32_16x16x32_bf16(a1, qf1, acc[m], 0, 0, 0);
    }

    float mx = -1e30f;
    #pragma unroll
    for (int m = 0; m < 16; ++m)
        mx = fmaxf(mx, fmaxf(fmaxf(acc[m][0], acc[m][1]), fmaxf(acc[m][2], acc[m][3])));
    mx = fmaxf(mx, __shfl_xor(mx, 16, 64));
    mx = fmaxf(mx, __shfl_xor(mx, 32, 64));

    __syncthreads();

    bf16* PtW = &KsPt[wave * 4224];
    float l_sum = 0.f;
    #pragma unroll
    for (int m = 0; m < 16; ++m) {
        bf16x4 pk;
        #pragma unroll
        for (int r = 0; r < 4; ++r) {
            const float p = __expf((acc[m][r] - mx) * 0.125f);
            l_sum += p;
            pk[r] = (bf16)p;
        }
        *(bf16x4*)&PtW[l15 * 264 + m * 16 + quad * 4] = pk;
    }
    l_sum += __shfl_xor(l_sum, 16, 64);
    l_sum += __shfl_xor(l_sum, 32, 64);
    __syncthreads();

    f32x4 oacc[4];
    #pragma unroll
    for (int m = 0; m < 4; ++m) oacc[m] = (f32x4){0.f, 0.f, 0.f, 0.f};
    #pragma unroll
    for (int s = 0; s < 8; ++s) {
        const bf16x8 pb = *(const bf16x8*)&PtW[l15 * 264 + s * 32 + quad * 8];
        #pragma unroll
        for (int m = 0; m < 4; ++m) {
            const bf16x8 va = *(const bf16x8*)&Vs[(m * 16 + l15) * 264 + s * 32 + quad * 8];
            oacc[m] = __builtin_amdgcn_mfma_f32_16x16x32_bf16(va, pb, oacc[m], 0, 0, 0);
        }
    }

    const float inv = 1.0f / l_sum;
    bf16* op = o + ((size_t)(b * HW + qrow)) * 512 + h * 64 + quad * 4;
    #pragma unroll
    for (int m = 0; m < 4; ++m) {
        bf16x4 ov;
        #pragma unroll
        for (int r = 0; r < 4; ++r) ov[r] = (bf16)(oacc[m][r] * inv);
        *(bf16x4*)&op[m * 16] = ov;
    }
}

// ---------------------------------------------------------------------------
// Fused out-projection + bias + residual + LayerNorm + transposed store.
// Block: 256 threads (4 waves), 32 s-rows x full N=512 -> grid 512 (2/CU).
// Wave w: n-range w*128 (j=0..7), all 32 s (i=0..1). Orientation mfma(af,bfr):
// lane&15 = c-within-chunk, quad*4+reg = s -> residual read and final store
// are 16B f32x4 at out[b][c][s] directly (no LDS transpose).
// ---------------------------------------------------------------------------
__global__ __launch_bounds__(256) void gemm_oln(
    const bf16* __restrict__ A,      // attn out [B*1024][512]
    const bf16* __restrict__ Wt,     // Wo^T [512][512]
    const float* __restrict__ bo,
    const float* __restrict__ img,   // raw residual [B][512][1024] f32
    const float* __restrict__ gamma, const float* __restrict__ beta,
    float* __restrict__ out)         // [B][512][1024]
{
    const int tid  = threadIdx.x;
    const int wave = tid >> 6, lane = tid & 63;
    const int l15 = lane & 15, quad = lane >> 4;
    const int m0 = blockIdx.x * 32;
    const int b  = m0 >> 10, s0 = m0 & 1023;
    const int wn = wave * 128;

    __shared__ bf16 As[32 * 32];
    __shared__ bf16 Bs[512 * 32];
    __shared__ float redS[2][32][4];   // [sum|sq][s][wave]

    const int r16 = lane >> 2;
    const int ks  = (lane & 3) * 8;

    f32x4 acc[2][8];
    #pragma unroll
    for (int i = 0; i < 2; ++i)
        #pragma unroll
        for (int j = 0; j < 8; ++j)
            acc[i][j] = (f32x4){0.f, 0.f, 0.f, 0.f};

    for (int k0 = 0; k0 < 512; k0 += 32) {
        #pragma unroll
        for (int t = 0; t < 8; ++t) {
            const int cb = wave * 8 + t;          // 0..31 chunks of 16 rows
            gl_lds16(Wt + (size_t)(cb * 16 + r16) * 512 + k0 + ks, &Bs[cb * 512]);
        }
        if (wave < 2)
            gl_lds16(A + (size_t)(m0 + wave * 16 + r16) * 512 + k0 + ks, &As[wave * 512]);
        __syncthreads();
        bf16x8 af[2], bfr[8];
        #pragma unroll
        for (int i = 0; i < 2; ++i)
            af[i] = *(const bf16x8*)&As[(i * 16 + l15) * 32 + quad * 8];
        #pragma unroll
        for (int j = 0; j < 8; ++j)
            bfr[j] = *(const bf16x8*)&Bs[(wn + j * 16 + l15) * 32 + quad * 8];
        #pragma unroll
        for (int i = 0; i < 2; ++i)
            #pragma unroll
            for (int j = 0; j < 8; ++j)
                acc[i][j] = __builtin_amdgcn_mfma_f32_16x16x32_bf16(af[i], bfr[j], acc[i][j], 0, 0, 0);
        __syncthreads();
    }

    // Pass 1: y = acc + bo + residual (f32); per-s partial stats
    float rs_[2][4] = {}, rq_[2][4] = {};
    #pragma unroll
    for (int j = 0; j < 8; ++j) {
        const int c = wn + j * 16 + l15;
        const float bo_c = bo[c];
        #pragma unroll
        for (int i = 0; i < 2; ++i) {
            const int sb = s0 + i * 16 + quad * 4;
            const f32x4 res = *(const f32x4*)(img + ((size_t)b * CCH + c) * HW + sb);
            #pragma unroll
            for (int r = 0; r < 4; ++r) {
                const float y = acc[i][j][r] + bo_c + res[r];
                acc[i][j][r] = y;
                rs_[i][r] += y;
                rq_[i][r] += y * y;
            }
        }
    }
    // reduce across the 16 l15 lanes (xor 1,2,4,8)
    #pragma unroll
    for (int i = 0; i < 2; ++i)
        #pragma unroll
        for (int r = 0; r < 4; ++r) {
            #pragma unroll
            for (int m = 1; m < 16; m <<= 1) {
                rs_[i][r] += __shfl_xor(rs_[i][r], m, 64);
                rq_[i][r] += __shfl_xor(rq_[i][r], m, 64);
            }
        }
    if (l15 == 0) {
        #pragma unroll
        for (int i = 0; i < 2; ++i)
            #pragma unroll
            for (int r = 0; r < 4; ++r) {
                redS[0][i * 16 + quad * 4 + r][wave] = rs_[i][r];
                redS[1][i * 16 + quad * 4 + r][wave] = rq_[i][r];
            }
    }
    __syncthreads();

    float mu[2][4], rstd[2][4];
    #pragma unroll
    for (int i = 0; i < 2; ++i)
        #pragma unroll
        for (int r = 0; r < 4; ++r) {
            const int s = i * 16 + quad * 4 + r;
            const float sm = redS[0][s][0] + redS[0][s][1] + redS[0][s][2] + redS[0][s][3];
            const float sq = redS[1][s][0] + redS[1][s][1] + redS[1][s][2] + redS[1][s][3];
            const float m_ = sm * (1.f / 512.f);
            mu[i][r] = m_;
            rstd[i][r] = rsqrtf(sq * (1.f / 512.f) - m_ * m_ + EPS);
        }

    // Pass 2: normalize + scale/shift + direct f32x4 store to [b][c][s]
    #pragma unroll
    for (int j = 0; j < 8; ++j) {
        const int c = wn + j * 16 + l15;
        const float g_c = gamma[c];
        const float be_c = beta[c];
        #pragma unroll
        for (int i = 0; i < 2; ++i) {
            const int sb = s0 + i * 16 + quad * 4;
            f32x4 z;
            #pragma unroll
            for (int r = 0; r < 4; ++r)
                z[r] = (acc[i][j][r] - mu[i][r]) * rstd[i][r] * g_c + be_c;
            *(f32x4*)(out + ((size_t)b * CCH + c) * HW + sb) = z;
        }
    }
}

// ---------------------------------------------------------------------------
extern "C" void kernel_launch(void* const* d_in, const int* in_sizes, int n_in,
                              void* d_out, int out_size, void* d_ws, size_t ws_size,
                              hipStream_t stream) {
    const float* img   = (const float*)d_in[0];
    const float* audio = (const float*)d_in[1];
    const float* Wq    = (const float*)d_in[2];
    const float* bq    = (const float*)d_in[3];
    const float* Wk    = (const float*)d_in[4];
    const float* bk    = (const float*)d_in[5];
    const float* Wv    = (const float*)d_in[6];
    const float* bv    = (const float*)d_in[7];
    const float* Wo    = (const float*)d_in[8];
    const float* bo    = (const float*)d_in[9];
    const float* gamma = (const float*)d_in[10];
    const float* beta  = (const float*)d_in[11];

    bf16* wsb    = (bf16*)d_ws;
    bf16* img_bf = wsb;                     // 8388608
    bf16* wT     = img_bf + 8388608;        // 4*262144 (q,k,v,o)
    bf16* q_bf   = wT + 1048576;            // 8388608
    bf16* kh_bf  = q_bf + 8388608;          // 2097152  [B][H][256][64]
    bf16* vt_bf  = kh_bf + 2097152;         // 2097152  [B][H][64][256]
    bf16* a_bf   = vt_bf + 2097152;         // 8388608

    transpose_cast_img<<<dim3(16, 8, 16), 256, 0, stream>>>(img, img_bf);
    transpose_cast_w<<<dim3(8, 8, 4), 256, 0, stream>>>(Wq, Wk, Wv, Wo, wT);

    // Q projection: M=16384, N=512
    gemm_bf16_mfma<<<dim3(128, 4), 256, 0, stream>>>(img_bf, wT, bq, q_bf);
    // K|V fused (raw f32 audio, cast in staging): M=4096, N=1024
    gemm_kv_mfma<<<dim3(32, 8), 256, 0, stream>>>(audio, wT + 262144, bk, bv, kh_bf, vt_bf);
    // MFMA attention
    attn_mfma<<<dim3(B_SZ * N_HEADS, HW / 64), 256, 0, stream>>>(q_bf, kh_bf, vt_bf, a_bf);
    // Fused out-projection + residual (raw f32 img) + LayerNorm + store
    gemm_oln<<<dim3(512), 256, 0, stream>>>(a_bf, wT + 3 * 262144, bo, img, gamma, beta, (float*)d_out);
}